// Round 7
// baseline (699.002 us; speedup 1.0000x reference)
//
#include <hip/hip_runtime.h>
#include <hip/hip_bf16.h>
#include <math.h>

// Problem constants (from reference)
constexpr int Bb   = 32;
constexpr int Ls   = 110;
constexpr int Gs   = 512;
constexpr int Ns   = 40;
constexpr int Ds   = 300;
constexpr int WPc  = 10;
constexpr int WFc  = 10;
constexpr int MAXNc = 110;
constexpr float EPSf  = 1e-8f;
constexpr float CLIPf = 1.0f - 1e-6f;
constexpr int BL = Bb * Ls;        // 3520
constexpr int Mrows = BL * Ns;     // 140800 flattened GEMM rows
constexpr int KST = 320;           // padded bf16 row stride (shorts), 16B-aligned
constexpr int RGRP = Mrows / 256;  // 550 row-groups of 256

typedef __attribute__((ext_vector_type(8))) short short8_t;
typedef __attribute__((ext_vector_type(4))) float floatx4;

__device__ __forceinline__ unsigned short bf16r(float f) {
  unsigned u = __float_as_uint(f);
  u += 0x7fffu + ((u >> 16) & 1u);          // RNE to bf16
  return (unsigned short)(u >> 16);
}

__device__ __forceinline__ unsigned pkbf(float lo, float hi) {
  unsigned a = __float_as_uint(lo), b = __float_as_uint(hi);
  a += 0x7fffu + ((a >> 16) & 1u);
  b += 0x7fffu + ((b >> 16) & 1u);
  return (a >> 16) | (b & 0xffff0000u);
}

__device__ __forceinline__ short8_t cvt8(const float4 v0, const float4 v1) {
  union { short8_t s; unsigned u[4]; } p;
  p.u[0] = pkbf(v0.x, v0.y);
  p.u[1] = pkbf(v0.z, v0.w);
  p.u[2] = pkbf(v1.x, v1.y);
  p.u[3] = pkbf(v1.z, v1.w);
  return p.s;
}

// ---------------------------------------------------------------------------
// Kernel 0: transpose W_sem (512x512) so the sem GEMM reads it coalesced.
// ---------------------------------------------------------------------------
__global__ __launch_bounds__(256) void transpose_wsem(const float* __restrict__ w,
                                                      float* __restrict__ wt) {
  __shared__ float tile[32][33];
  const int bx = blockIdx.x * 32;
  const int by = blockIdx.y * 32;
  const int tx = threadIdx.x;   // 0..31
  const int ty = threadIdx.y;   // 0..7
#pragma unroll
  for (int r = ty; r < 32; r += 8)
    tile[r][tx] = w[(by + r) * Gs + (bx + tx)];
  __syncthreads();
#pragma unroll
  for (int r = ty; r < 32; r += 8)
    wt[(bx + r) * Gs + (by + tx)] = tile[tx][r];   // wt[t][s] = w[s][t]
}

// ---------------------------------------------------------------------------
// Kernel 0b: Wc -> MFMA-fragment-major bf16 table.
// wctf[((nb*10 + c)*64 + lane)*8 + e] = bf16(Wc[s][t]), zero-padded,
//   s = c*32 + (lane>>4)*8 + e,  t = nb*16 + (lane&15).
// A wave's B-fragment for (nb, c) is ONE coalesced 1 KB dwordx4 load;
// 200 KB total, L2-resident, shared by every block of con_stage.
// ---------------------------------------------------------------------------
__global__ __launch_bounds__(64) void wctf_prep(const float* __restrict__ wc,
                                                short* __restrict__ wctf) {
  const int fid = blockIdx.x;       // nb*10 + c, 200 total
  const int nb = fid / 10, c = fid % 10;
  const int lane = threadIdx.x;
  const int t = nb * 16 + (lane & 15);
  const int s0 = c * 32 + (lane >> 4) * 8;
  short8_t v;
#pragma unroll
  for (int e = 0; e < 8; ++e) {
    const int s = s0 + e;
    const float f = (s < Ds && t < Ds) ? wc[s * Ds + t] : 0.f;
    v[e] = (short)bf16r(f);
  }
  *reinterpret_cast<short8_t*>(wctf + ((size_t)fid * 64 + lane) * 8) = v;
}

// ---------------------------------------------------------------------------
// Kernel 1: att_sem[bl,s] = sum_t W[s,t] * x[bl,t]
// ---------------------------------------------------------------------------
__global__ __launch_bounds__(512) void sem_gemm(const float* __restrict__ nf,
                                                const float* __restrict__ wt,
                                                float* __restrict__ att_sem,
                                                float* __restrict__ na_arr) {
  const int bl0 = blockIdx.x * 8;
  const int s = threadIdx.x;
  const float* __restrict__ x0 = nf + (size_t)bl0 * Gs;
  float acc[8];
#pragma unroll
  for (int r = 0; r < 8; ++r) acc[r] = 0.f;
#pragma unroll 4
  for (int t = 0; t < Gs; ++t) {
    const float wv = wt[t * Gs + s];
#pragma unroll
    for (int r = 0; r < 8; ++r) acc[r] = fmaf(wv, x0[r * Gs + t], acc[r]);
  }
#pragma unroll
  for (int r = 0; r < 8; ++r) att_sem[(size_t)(bl0 + r) * Gs + s] = acc[r];

  __shared__ float partial[8][8];
  const int wave = s >> 6, lane = s & 63;
#pragma unroll
  for (int r = 0; r < 8; ++r) {
    float v = acc[r] * acc[r];
#pragma unroll
    for (int off = 32; off > 0; off >>= 1) v += __shfl_xor(v, off);
    if (lane == 0) partial[r][wave] = v;
  }
  __syncthreads();
  if (s < 8) {
    float sum = 0.f;
#pragma unroll
    for (int w2 = 0; w2 < 8; ++w2) sum += partial[s][w2];
    na_arr[bl0 + s] = fmaxf(sqrtf(sum), EPSf);
  }
}

// ---------------------------------------------------------------------------
// Kernel 2: banded semantic attention + softmax. One block per (b,j).
// Writes the FULL output row (zeros outside window) -> serves as out init.
// ---------------------------------------------------------------------------
__global__ __launch_bounds__(256) void sem_attn(const float* __restrict__ nf,
                                                const float* __restrict__ att_sem,
                                                const float* __restrict__ na_arr,
                                                const int* __restrict__ tlen,
                                                float* __restrict__ out) {
  const int blk = blockIdx.x;
  const int b = blk / Ls, j = blk % Ls;
  const int len = tlen[b];
  float* __restrict__ orow = out + (size_t)(b * Ls + j) * MAXNc;
  if (j >= len) {
    for (int k = threadIdx.x; k < MAXNc; k += 256) orow[k] = 0.f;
    return;
  }
  const int k0 = max(j - WPc, 0);
  const int k1 = min(j + WFc, len - 1);
  const int nk = k1 - k0 + 1;   // <= 21

  __shared__ float xs[Gs];
  __shared__ float sc[21];
  __shared__ float red[4];

  const float* __restrict__ x = nf + (size_t)(b * Ls + j) * Gs;
  float ss = 0.f;
  for (int t = threadIdx.x; t < Gs; t += 256) {
    const float v = x[t];
    xs[t] = v;
    ss += v * v;
  }
  const int wave = threadIdx.x >> 6, lane = threadIdx.x & 63;
#pragma unroll
  for (int off = 32; off > 0; off >>= 1) ss += __shfl_xor(ss, off);
  if (lane == 0) red[wave] = ss;
  __syncthreads();
  const float nfn = fmaxf(sqrtf(red[0] + red[1] + red[2] + red[3]), EPSf);

  for (int i = wave; i < nk; i += 4) {
    const int k = k0 + i;
    const float* __restrict__ as = att_sem + (size_t)(b * Ls + k) * Gs;
    float d = 0.f;
#pragma unroll
    for (int t = lane; t < Gs; t += 64) d = fmaf(xs[t], as[t], d);
#pragma unroll
    for (int off = 32; off > 0; off >>= 1) d += __shfl_xor(d, off);
    if (lane == 0) {
      float cs = d / (nfn * na_arr[b * Ls + k]);
      cs = fminf(fmaxf(cs, -CLIPf), CLIPf);
      sc[i] = 1.0f - acosf(cs) * (float)(1.0 / M_PI);
    }
  }
  __syncthreads();
  if (threadIdx.x == 0) {
    float m = -1e30f;
    for (int i = 0; i < nk; ++i) m = fmaxf(m, sc[i]);
    red[0] = m;
  }
  __syncthreads();
  const float m = red[0];
  if ((int)threadIdx.x < nk) sc[threadIdx.x] = expf(sc[threadIdx.x] - m);
  __syncthreads();
  if (threadIdx.x == 0) {
    float s = 0.f;
    for (int i = 0; i < nk; ++i) s += sc[i];
    red[1] = 1.0f / fmaxf(s, EPSf);
  }
  __syncthreads();
  const float inv = red[1];
  for (int k = threadIdx.x; k < MAXNc; k += 256) {
    float v = 0.f;
    if (k >= k0 && k <= k1) v = 0.5f * sc[k - k0] * inv;
    orow[k] = v;
  }
}

// ---------------------------------------------------------------------------
// Kernel 3 (round-13): MERGED kn_prep + con_gemm along the STREAMING axis.
// Reads fp32 kn once (A-fragment pattern, 4 XCD-colocated partners share via
// L2); the in-loop cvt8 result is BOTH the MFMA A-operand and the knb store
// (m==0 partner only), so the separate kn_prep pass disappears. fp32-exact
// row ssq -> kninv for free. Keeps r5's proven inner loop: 4 row-tiles/wave,
// wctf fragment-major B (no LDS, NO barrier), 20 MFMAs per chunk.
// __launch_bounds__(256,2): cap 256 regs (~190 live) -> spill IMPOSSIBLE
// (r2 lesson); no barrier -> ILP carries latency at 2 blocks/CU.
// ---------------------------------------------------------------------------
__global__ __launch_bounds__(256, 2) void con_stage(const float* __restrict__ kn,
                                                    const short* __restrict__ wctf,
                                                    const int* __restrict__ tlen,
                                                    unsigned short* __restrict__ knb,
                                                    float* __restrict__ kninv,
                                                    unsigned short* __restrict__ ybar,
                                                    float* __restrict__ rowss) {
  // swizzle decode: xcd = lin%8; partners m=0..3 of group g sit 8 apart
  const int lin = blockIdx.x;
  const int xcd = lin & 7, slot = lin >> 3;
  const int m = slot & 3;
  const int g = xcd + 8 * (slot >> 2);
  if (g >= RGRP) return;
  const int rowbase = g * 256;
  const int n0 = m * 80;

  const int tid = threadIdx.x;
  const int wave = tid >> 6, lane = tid & 63;
  const int quad = lane >> 4, l16 = lane & 15;
  const int wrow = rowbase + wave * 64;   // 64 rows per wave

  // wave-level liveness over the 64 rows (no barriers anywhere -> safe)
  {
    bool any = false;
    for (int bl = wrow / Ns; bl <= (wrow + 63) / Ns; ++bl)
      any |= (bl % Ls) < tlen[bl / Ls];
    if (!any) return;
  }

  const short* __restrict__ bbase = wctf + (size_t)(m * 5) * 5120;  // nb0*10*64*8

  const float* arow[4];
  unsigned short* krow[4];
#pragma unroll
  for (int tt = 0; tt < 4; ++tt) {
    const int row = wrow + tt * 16 + l16;
    arow[tt] = kn + (size_t)row * Ds + quad * 8;
    krow[tt] = knb + (size_t)row * KST + quad * 8;
  }

  floatx4 acc[4][5];
#pragma unroll
  for (int tt = 0; tt < 4; ++tt)
#pragma unroll
    for (int i = 0; i < 5; ++i) acc[tt][i] = (floatx4){0.f, 0.f, 0.f, 0.f};

  float ssq[4] = {0.f, 0.f, 0.f, 0.f};

  // preload + convert + store chunk 0 (full: quad*8 + 7 <= 31 < 300)
  short8_t Af[2][4];
#pragma unroll
  for (int tt = 0; tt < 4; ++tt) {
    const float4 v0 = *reinterpret_cast<const float4*>(arow[tt]);
    const float4 v1 = *reinterpret_cast<const float4*>(arow[tt] + 4);
    ssq[tt] += v0.x * v0.x + v0.y * v0.y + v0.z * v0.z + v0.w * v0.w +
               v1.x * v1.x + v1.y * v1.y + v1.z * v1.z + v1.w * v1.w;
    Af[0][tt] = cvt8(v0, v1);
    if (m == 0) *reinterpret_cast<short8_t*>(krow[tt]) = Af[0][tt];
  }

#pragma unroll
  for (int c = 0; c < 10; ++c) {
    // B fragments for this chunk: 5 coalesced L2-hot 1 KB loads
    short8_t bfr[5];
#pragma unroll
    for (int i = 0; i < 5; ++i)
      bfr[i] = *reinterpret_cast<const short8_t*>(
          bbase + ((size_t)(i * 10 + c) * 64 + lane) * 8);
    // issue fp32 A loads for chunk c+1 (consumed after the MFMA block)
    float4 F0[4], F1[4];
    if (c < 8) {
#pragma unroll
      for (int tt = 0; tt < 4; ++tt) {
        F0[tt] = *reinterpret_cast<const float4*>(arow[tt] + (c + 1) * 32);
        F1[tt] = *reinterpret_cast<const float4*>(arow[tt] + (c + 1) * 32 + 4);
      }
    } else if (c == 8) {   // tail chunk 9: element base 288 (+quad*8 in arow)
#pragma unroll
      for (int tt = 0; tt < 4; ++tt) {
        float4 v0 = make_float4(0.f, 0.f, 0.f, 0.f);
        float4 v1 = make_float4(0.f, 0.f, 0.f, 0.f);
        if (quad == 0) {               // 288..295 valid
          v0 = *reinterpret_cast<const float4*>(arow[tt] + 288);
          v1 = *reinterpret_cast<const float4*>(arow[tt] + 292);
        } else if (quad == 1) {        // 296..299 valid (arow has +quad*8)
          v0 = *reinterpret_cast<const float4*>(arow[tt] + 288);
        }
        F0[tt] = v0;
        F1[tt] = v1;
      }
    }
    // 20 MFMAs: each B fragment reused by 4 tiles; A from the bf16 ring
#pragma unroll
    for (int i = 0; i < 5; ++i)
#pragma unroll
      for (int tt = 0; tt < 4; ++tt)
        acc[tt][i] = __builtin_amdgcn_mfma_f32_16x16x32_bf16(Af[c & 1][tt], bfr[i],
                                                             acc[tt][i], 0, 0, 0);
    // consume chunk c+1: ssq, convert into ring, store knb
    if (c < 9) {
#pragma unroll
      for (int tt = 0; tt < 4; ++tt) {
        ssq[tt] += F0[tt].x * F0[tt].x + F0[tt].y * F0[tt].y +
                   F0[tt].z * F0[tt].z + F0[tt].w * F0[tt].w +
                   F1[tt].x * F1[tt].x + F1[tt].y * F1[tt].y +
                   F1[tt].z * F1[tt].z + F1[tt].w * F1[tt].w;
        Af[(c + 1) & 1][tt] = cvt8(F0[tt], F1[tt]);
        if (m == 0)
          *reinterpret_cast<short8_t*>(krow[tt] + (c + 1) * 32) =
              Af[(c + 1) & 1][tt];
      }
    }
  }

  // epilogue: kninv + per-tile liveness guard; row-ssq atomics + bf16 store
  // C layout: col = l16 (+16i), row = quad*4 + r
#pragma unroll
  for (int tt = 0; tt < 4; ++tt) {
    const int row0 = wrow + tt * 16;

    // full-row kn ssq (fp32-exact): reduce over the 4 quads (same l16)
    float sq = ssq[tt];
    sq += __shfl_xor(sq, 16);
    sq += __shfl_xor(sq, 32);
    if (m == 0 && lane < 16)   // quad 0, l16 = lane
      kninv[row0 + lane] = 1.0f / fmaxf(sqrtf(sq), EPSf);

    const int blA = row0 / Ns, blB = (row0 + 15) / Ns;
    const bool alive = ((blA % Ls) < tlen[blA / Ls]) | ((blB % Ls) < tlen[blB / Ls]);
    if (!alive) continue;

#pragma unroll
    for (int r = 0; r < 4; ++r) {
      float p = 0.f;
#pragma unroll
      for (int i = 0; i < 5; ++i) p = fmaf(acc[tt][i][r], acc[tt][i][r], p);
      p += __shfl_xor(p, 1);
      p += __shfl_xor(p, 2);
      p += __shfl_xor(p, 4);
      p += __shfl_xor(p, 8);
      if (l16 == 0) atomicAdd(&rowss[row0 + quad * 4 + r], p);
    }
#pragma unroll
    for (int i = 0; i < 5; ++i) {
      const int col = n0 + i * 16 + l16;   // < 320 always
#pragma unroll
      for (int r = 0; r < 4; ++r)
        ybar[(size_t)(row0 + quad * 4 + r) * KST + col] = bf16r(acc[tt][i][r]);
    }
  }
}

// ---------------------------------------------------------------------------
// Kernel 4: banded contextual attention via MFMA banded Gram.
// r5 body unchanged (bf16 knb A-side, kninv precomputed, wctf-era numerics).
// XCD swizzle: 7 jt-tiles of one b colocate; 4 consecutive b per XCD ->
// per-b knb/ybar window stays L2-resident across the 3x band overlap.
// ---------------------------------------------------------------------------
__global__ __launch_bounds__(512) void con_attn_mfma(const unsigned short* __restrict__ knb,
                                                     const unsigned short* __restrict__ ybar,
                                                     const float* __restrict__ rowss,
                                                     const float* __restrict__ kninv,
                                                     const float* __restrict__ anew,
                                                     const int* __restrict__ tlen,
                                                     float* __restrict__ out) {
  const int lin = blockIdx.x;          // 224 = 8 xcd * 28 slots
  const int xcd = lin & 7, slot = lin >> 3;
  const int b = xcd * 4 + slot / 7;
  const int jt = slot % 7;
  const int j0 = jt * 16;
  const int len = tlen[b];
  if (j0 >= len) return;                       // rows already zeroed by sem_attn
  const int kbase = min(max(j0 - WPc, 0), Ls - 48);   // 48-window always in-range

  const int tid = threadIdx.x;
  const int wave = tid >> 6, lane = tid & 63;
  const int quad = lane >> 4, l16 = lane & 15;

  __shared__ float red[8][768];   // 24 KB: per-wave partial 16x48 tiles

  const int jj = min(j0 + l16, Ls - 1);        // A-row clamp (tile may overhang L)
  const size_t blj = (size_t)(b * Ls + jj);

  float outacc[3][4];
#pragma unroll
  for (int t = 0; t < 3; ++t)
#pragma unroll
    for (int r = 0; r < 4; ++r) outacc[t][r] = 0.f;

  const unsigned short* yrow[3];
  int krow_m[3];    // flattened GEMM row index base for (k, n=0)
#pragma unroll
  for (int t = 0; t < 3; ++t) {
    const int k = kbase + t * 16 + l16;
    yrow[t] = ybar + (size_t)(b * Ls + k) * Ns * KST;
    krow_m[t] = (b * Ls + k) * Ns;
  }

  for (int ni = 0; ni < 5; ++ni) {
    const int n = wave + ni * 8;
    const unsigned short* __restrict__ arow =
        knb + ((blj * Ns + n) * (size_t)KST) + quad * 8;

    // per-(k,n) weight: issue loads early, math is cheap
    float w_t[3];
#pragma unroll
    for (int t = 0; t < 3; ++t) {
      const int mm = krow_m[t] + n;
      const float a = anew[mm];
      const float ssqk = rowss[mm];
      const float aff = (sqrtf((a - 0.5f) * (a - 0.5f) + 0.25f * a * a) - 0.06467f) *
                        (1.0f / 0.607468f);
      w_t[t] = aff / fmaxf(aff * sqrtf(ssqk), EPSf);
    }
    const float kinv = kninv[blj * Ns + n];   // fp32-exact 1/||kn(j,n)||

    floatx4 S[3];
#pragma unroll
    for (int t = 0; t < 3; ++t) S[t] = (floatx4){0.f, 0.f, 0.f, 0.f};

#pragma unroll
    for (int c = 0; c < 10; ++c) {
      const short8_t afrag = *reinterpret_cast<const short8_t*>(arow + c * 32);
#pragma unroll
      for (int t = 0; t < 3; ++t) {
        const short8_t bfrag = *reinterpret_cast<const short8_t*>(
            yrow[t] + (size_t)n * KST + c * 32 + quad * 8);
        S[t] = __builtin_amdgcn_mfma_f32_16x16x32_bf16(afrag, bfrag, S[t], 0, 0, 0);
      }
    }

#pragma unroll
    for (int r = 0; r < 4; ++r) {
      const float kv = __shfl(kinv, quad * 4 + r);
#pragma unroll
      for (int t = 0; t < 3; ++t)
        outacc[t][r] = fmaf(kv * w_t[t], fabsf(S[t][r]), outacc[t][r]);
    }
  }

#pragma unroll
  for (int t = 0; t < 3; ++t)
#pragma unroll
    for (int r = 0; r < 4; ++r)
      red[wave][(quad * 4 + r) * 48 + t * 16 + l16] = outacc[t][r];
  __syncthreads();

  for (int idx = tid; idx < 768; idx += 512) {
    float s = 0.f;
#pragma unroll
    for (int w = 0; w < 8; ++w) s += red[w][idx];
    const int j = j0 + idx / 48;
    const int k = kbase + idx % 48;
    if (j < len && k < len && k >= j - WPc && k <= j + WFc)
      out[(size_t)(b * Ls + j) * MAXNc + k] += 5.0f * s;   // 0.5 * 10
  }
}

// ---------------------------------------------------------------------------
extern "C" void kernel_launch(void* const* d_in, const int* in_sizes, int n_in,
                              void* d_out, int out_size, void* d_ws, size_t ws_size,
                              hipStream_t stream) {
  const float* nf   = (const float*)d_in[0];   // (B,L,G)
  const float* kn   = (const float*)d_in[1];   // (B,L,N,D)
  const float* anew = (const float*)d_in[2];   // (B,L,N)
  const float* wsem = (const float*)d_in[3];   // (G,G)
  const float* wcon = (const float*)d_in[4];   // (D,D)
  const int*   tlen = (const int*)d_in[5];     // (B,)
  float* out = (float*)d_out;

  // workspace layout (~190 MB)
  float* att_sem = (float*)d_ws;                            // 3520*512 f32
  float* na_arr  = att_sem + (size_t)BL * Gs;               // 3520 f32
  float* wt      = na_arr + BL;                             // 512*512 f32
  short* wctf    = (short*)(wt + (size_t)Gs * Gs);          // 200*64*8 bf16 (200 KB)
  float* rowss   = (float*)(wctf + 200 * 64 * 8);           // Mrows f32
  float* kninv   = rowss + Mrows;                           // Mrows f32
  unsigned short* knb  = (unsigned short*)(kninv + Mrows);  // Mrows*320 bf16
  unsigned short* ybar = knb + (size_t)Mrows * KST;         // Mrows*320 bf16

  hipMemsetAsync(rowss, 0, (size_t)Mrows * sizeof(float), stream);
  transpose_wsem<<<dim3(16, 16), dim3(32, 8), 0, stream>>>(wsem, wt);
  wctf_prep<<<200, 64, 0, stream>>>(wcon, wctf);
  sem_gemm<<<BL / 8, 512, 0, stream>>>(nf, wt, att_sem, na_arr);
  sem_attn<<<BL, 256, 0, stream>>>(nf, att_sem, na_arr, tlen, out);
  // 2208 = 8 XCDs * 276 slots; g-guard trims the 2 spare groups
  con_stage<<<2208, 256, 0, stream>>>(kn, wctf, tlen, knb, kninv, ybar, rowss);
  con_attn_mfma<<<Bb * 7, 512, 0, stream>>>(knb, ybar, rowss, kninv, anew, tlen, out);
}

// Round 8
// 501.054 us; speedup vs baseline: 1.3951x; 1.3951x over previous
//
#include <hip/hip_runtime.h>
#include <hip/hip_bf16.h>
#include <math.h>

// Problem constants (from reference)
constexpr int Bb   = 32;
constexpr int Ls   = 110;
constexpr int Gs   = 512;
constexpr int Ns   = 40;
constexpr int Ds   = 300;
constexpr int WPc  = 10;
constexpr int WFc  = 10;
constexpr int MAXNc = 110;
constexpr float EPSf  = 1e-8f;
constexpr float CLIPf = 1.0f - 1e-6f;
constexpr int BL = Bb * Ls;        // 3520
constexpr int Mrows = BL * Ns;     // 140800 flattened GEMM rows
constexpr int BPITCH = 328;        // LDS B pitch in shorts
constexpr int KST = 320;           // padded bf16 row stride (shorts)
constexpr int RGRP = Mrows / 256;  // 550 row-groups of 256

// fused-grid partition points
constexpr int PREP_BLOCKS = 2048;          // kn_prep part (512 thr)
constexpr int SGEMM_BLOCKS = BL / 8;       // 440
constexpr int CGEMM_BLOCKS = 2208;         // 8 XCDs * 276 slots

typedef __attribute__((ext_vector_type(8))) short short8_t;
typedef __attribute__((ext_vector_type(4))) float floatx4;

__device__ __forceinline__ unsigned short bf16r(float f) {
  unsigned u = __float_as_uint(f);
  u += 0x7fffu + ((u >> 16) & 1u);          // RNE to bf16
  return (unsigned short)(u >> 16);
}

__device__ __forceinline__ unsigned pkbf(float lo, float hi) {
  unsigned a = __float_as_uint(lo), b = __float_as_uint(hi);
  a += 0x7fffu + ((a >> 16) & 1u);
  b += 0x7fffu + ((b >> 16) & 1u);
  return (a >> 16) | (b & 0xffff0000u);
}

__device__ __forceinline__ short8_t cvt8(const float4 v0, const float4 v1) {
  union { short8_t s; unsigned u[4]; } p;
  p.u[0] = pkbf(v0.x, v0.y);
  p.u[1] = pkbf(v0.z, v0.w);
  p.u[2] = pkbf(v1.x, v1.y);
  p.u[3] = pkbf(v1.z, v1.w);
  return p.s;
}

// ---------------------------------------------------------------------------
// Kernel 0: transpose W_sem (512x512) so the sem GEMM reads it coalesced.
// ---------------------------------------------------------------------------
__global__ __launch_bounds__(256) void transpose_wsem(const float* __restrict__ w,
                                                      float* __restrict__ wt) {
  __shared__ float tile[32][33];
  const int bx = blockIdx.x * 32;
  const int by = blockIdx.y * 32;
  const int tx = threadIdx.x;   // 0..31
  const int ty = threadIdx.y;   // 0..7
#pragma unroll
  for (int r = ty; r < 32; r += 8)
    tile[r][tx] = w[(by + r) * Gs + (bx + tx)];
  __syncthreads();
#pragma unroll
  for (int r = ty; r < 32; r += 8)
    wt[(bx + r) * Gs + (by + tx)] = tile[tx][r];   // wt[t][s] = w[s][t]
}

// ---------------------------------------------------------------------------
// Kernel 0b: WcT[t][s] = bf16(Wc[s][t]), zero-padded to [320][320].
// ---------------------------------------------------------------------------
__global__ __launch_bounds__(256) void wct_prep(const float* __restrict__ wc,
                                                short* __restrict__ wct) {
  __shared__ float tile[32][33];
  const int t0 = blockIdx.x * 32;   // t tile
  const int s0 = blockIdx.y * 32;   // s tile
  const int tx = threadIdx.x, ty = threadIdx.y;
#pragma unroll
  for (int r = ty; r < 32; r += 8) {
    const int s = s0 + r, t = t0 + tx;
    tile[r][tx] = (s < Ds && t < Ds) ? wc[s * Ds + t] : 0.f;
  }
  __syncthreads();
#pragma unroll
  for (int r = ty; r < 32; r += 8) {
    const int t = t0 + r, s = s0 + tx;
    wct[t * KST + s] = (short)bf16r(tile[tx][r]);
  }
}

// ---------------------------------------------------------------------------
// FUSED 1: kn_prep (blocks [0,2048)) CONCURRENT WITH sem_gemm (blocks
// [2048,2488)). kn_prep saturates HBM (pure BW); sem_gemm is L2/VALU-bound
// and hides underneath. Bodies identical to the round-1 proven kernels;
// block-uniform branch, barriers only inside the sem_gemm branch.
// ---------------------------------------------------------------------------
__global__ __launch_bounds__(512) void fused_prep_semgemm(
    const float* __restrict__ kn, unsigned short* __restrict__ knb,
    float* __restrict__ kninv,
    const float* __restrict__ nf, const float* __restrict__ wt,
    float* __restrict__ att_sem, float* __restrict__ na_arr) {
  __shared__ float partial[8][8];

  if (blockIdx.x < PREP_BLOCKS) {
    // ---- kn_prep: fp32 -> bf16 [Mrows][320] + fp32-exact row inv-norms ----
    const int wid = (blockIdx.x * 512 + threadIdx.x) >> 6;
    const int lane = threadIdx.x & 63;
    const int nwaves = PREP_BLOCKS * 8;
    for (int row = wid; row < Mrows; row += nwaves) {
      const float* __restrict__ src = kn + (size_t)row * Ds;
      float4 v0 = make_float4(0.f, 0.f, 0.f, 0.f);
      float4 v1 = v0;
      const int d0 = lane * 8;
      if (lane < 37) {                      // d0+7 <= 295 < 300 : full
        v0 = *reinterpret_cast<const float4*>(src + d0);
        v1 = *reinterpret_cast<const float4*>(src + d0 + 4);
      } else if (lane == 37) {              // d 296..299 valid, 300..303 zero
        v0 = *reinterpret_cast<const float4*>(src + d0);
      }
      float ss = v0.x * v0.x + v0.y * v0.y + v0.z * v0.z + v0.w * v0.w +
                 v1.x * v1.x + v1.y * v1.y + v1.z * v1.z + v1.w * v1.w;
#pragma unroll
      for (int off = 32; off > 0; off >>= 1) ss += __shfl_xor(ss, off);
      if (lane < 40)
        *reinterpret_cast<short8_t*>(knb + (size_t)row * KST + d0) = cvt8(v0, v1);
      if (lane == 0) kninv[row] = 1.0f / fmaxf(sqrtf(ss), EPSf);
    }
  } else {
    // ---- sem_gemm: att_sem[bl,s] = sum_t W[s,t] * x[bl,t] ----
    const int bl0 = (blockIdx.x - PREP_BLOCKS) * 8;
    const int s = threadIdx.x;
    const float* __restrict__ x0 = nf + (size_t)bl0 * Gs;
    float acc[8];
#pragma unroll
    for (int r = 0; r < 8; ++r) acc[r] = 0.f;
#pragma unroll 4
    for (int t = 0; t < Gs; ++t) {
      const float wv = wt[t * Gs + s];
#pragma unroll
      for (int r = 0; r < 8; ++r) acc[r] = fmaf(wv, x0[r * Gs + t], acc[r]);
    }
#pragma unroll
    for (int r = 0; r < 8; ++r) att_sem[(size_t)(bl0 + r) * Gs + s] = acc[r];

    const int wave = s >> 6, lane = s & 63;
#pragma unroll
    for (int r = 0; r < 8; ++r) {
      float v = acc[r] * acc[r];
#pragma unroll
      for (int off = 32; off > 0; off >>= 1) v += __shfl_xor(v, off);
      if (lane == 0) partial[r][wave] = v;
    }
    __syncthreads();
    if (s < 8) {
      float sum = 0.f;
#pragma unroll
      for (int w2 = 0; w2 < 8; ++w2) sum += partial[s][w2];
      na_arr[bl0 + s] = fmaxf(sqrtf(sum), EPSf);
    }
  }
}

// ---------------------------------------------------------------------------
// FUSED 2: con_gemm (blocks [0,2208), round-1 proven body: knb A-side ring-3,
// LDS-staged B, 4 row-tiles/wave) CONCURRENT WITH sem_attn (blocks
// [2208,5728)). sem_attn's ~2 KB of LDS overlays con_gemm's 52.5 KB Bl so
// the static footprint stays 3 blocks/CU. Mixed-role co-residency raises
// waves/CU for both latency-bound bodies. sem_attn writes the full out rows
// (init) -> con_attn (next kernel) accumulates safely afterward.
// ---------------------------------------------------------------------------
__global__ __launch_bounds__(256, 3) void fused_congemm_semattn(
    const unsigned short* __restrict__ knb, const short* __restrict__ wct,
    const int* __restrict__ tlen,
    unsigned short* __restrict__ ybar, float* __restrict__ rowss,
    const float* __restrict__ nf, const float* __restrict__ att_sem,
    const float* __restrict__ na_arr, float* __restrict__ out) {
  __shared__ short Bl[80 * BPITCH];   // 52.5 KB; overlaid by sem_attn branch
  __shared__ float sred[4];
  __shared__ float ssc[21];

  if (blockIdx.x < CGEMM_BLOCKS) {
    // ---- con_gemm (r1 body) ----
    const int lin = blockIdx.x;
    const int xcd = lin & 7, slot = lin >> 3;
    const int m = slot & 3;
    const int g = xcd + 8 * (slot >> 2);
    if (g >= RGRP) return;
    const int rowbase = g * 256;
    const int n0 = m * 80;

    const int tid = threadIdx.x;
    for (int s = tid; s < 80 * 40; s += 256) {
      const int nl = s / 40, sl = s % 40;
      *reinterpret_cast<short8_t*>(&Bl[nl * BPITCH + sl * 8]) =
          *reinterpret_cast<const short8_t*>(wct + (n0 + nl) * KST + sl * 8);
    }
    __syncthreads();   // the only barrier in this branch

    const int wave = tid >> 6, lane = tid & 63;
    const int quad = lane >> 4, l16 = lane & 15;
    const int wrow = rowbase + wave * 64;   // 64 rows per wave

    {
      bool any = false;
      for (int bl = wrow / Ns; bl <= (wrow + 63) / Ns; ++bl)
        any |= (bl % Ls) < tlen[bl / Ls];
      if (!any) return;   // barrier already passed; safe
    }

    const unsigned short* arow[4];
#pragma unroll
    for (int tt = 0; tt < 4; ++tt)
      arow[tt] = knb + (size_t)(wrow + tt * 16 + l16) * KST + quad * 8;

    floatx4 acc[4][5];
#pragma unroll
    for (int tt = 0; tt < 4; ++tt)
#pragma unroll
      for (int i = 0; i < 5; ++i) acc[tt][i] = (floatx4){0.f, 0.f, 0.f, 0.f};

    // ring-3 A prefetch (uniform chunks thanks to knb zero-padding)
    short8_t A[3][4];
#pragma unroll
    for (int tt = 0; tt < 4; ++tt) {
      A[0][tt] = *reinterpret_cast<const short8_t*>(arow[tt]);
      A[1][tt] = *reinterpret_cast<const short8_t*>(arow[tt] + 32);
    }

#pragma unroll
    for (int c = 0; c < 10; ++c) {
      if (c < 8) {
#pragma unroll
        for (int tt = 0; tt < 4; ++tt)
          A[(c + 2) % 3][tt] =
              *reinterpret_cast<const short8_t*>(arow[tt] + (c + 2) * 32);
      }
#pragma unroll
      for (int i = 0; i < 5; ++i) {
        const short8_t bfrag = *reinterpret_cast<const short8_t*>(
            &Bl[(i * 16 + l16) * BPITCH + c * 32 + quad * 8]);
#pragma unroll
        for (int tt = 0; tt < 4; ++tt)
          acc[tt][i] = __builtin_amdgcn_mfma_f32_16x16x32_bf16(
              A[c % 3][tt], bfrag, acc[tt][i], 0, 0, 0);
      }
    }

    // epilogue: per-tile liveness guard; row-ssq atomics + bf16 store
#pragma unroll
    for (int tt = 0; tt < 4; ++tt) {
      const int row0 = wrow + tt * 16;
      const int blA = row0 / Ns, blB = (row0 + 15) / Ns;
      const bool alive =
          ((blA % Ls) < tlen[blA / Ls]) | ((blB % Ls) < tlen[blB / Ls]);
      if (!alive) continue;

#pragma unroll
      for (int r = 0; r < 4; ++r) {
        float p = 0.f;
#pragma unroll
        for (int i = 0; i < 5; ++i) p = fmaf(acc[tt][i][r], acc[tt][i][r], p);
        p += __shfl_xor(p, 1);
        p += __shfl_xor(p, 2);
        p += __shfl_xor(p, 4);
        p += __shfl_xor(p, 8);
        if (l16 == 0) atomicAdd(&rowss[row0 + quad * 4 + r], p);
      }
#pragma unroll
      for (int i = 0; i < 5; ++i) {
        const int col = n0 + i * 16 + l16;   // < 320 always
#pragma unroll
        for (int r = 0; r < 4; ++r)
          ybar[(size_t)(row0 + quad * 4 + r) * KST + col] = bf16r(acc[tt][i][r]);
      }
    }
  } else {
    // ---- sem_attn (r1 body; xs overlaid on Bl) ----
    float* xs = reinterpret_cast<float*>(Bl);   // 512 floats = 2 KB < 52.5 KB
    const int blk = blockIdx.x - CGEMM_BLOCKS;
    const int b = blk / Ls, j = blk % Ls;
    const int len = tlen[b];
    float* __restrict__ orow = out + (size_t)(b * Ls + j) * MAXNc;
    if (j >= len) {
      for (int k = threadIdx.x; k < MAXNc; k += 256) orow[k] = 0.f;
      return;
    }
    const int k0 = max(j - WPc, 0);
    const int k1 = min(j + WFc, len - 1);
    const int nk = k1 - k0 + 1;   // <= 21

    const float* __restrict__ x = nf + (size_t)(b * Ls + j) * Gs;
    float ss = 0.f;
    for (int t = threadIdx.x; t < Gs; t += 256) {
      const float v = x[t];
      xs[t] = v;
      ss += v * v;
    }
    const int wave = threadIdx.x >> 6, lane = threadIdx.x & 63;
#pragma unroll
    for (int off = 32; off > 0; off >>= 1) ss += __shfl_xor(ss, off);
    if (lane == 0) sred[wave] = ss;
    __syncthreads();
    const float nfn = fmaxf(sqrtf(sred[0] + sred[1] + sred[2] + sred[3]), EPSf);

    for (int i = wave; i < nk; i += 4) {
      const int k = k0 + i;
      const float* __restrict__ as = att_sem + (size_t)(b * Ls + k) * Gs;
      float d = 0.f;
#pragma unroll
      for (int t = lane; t < Gs; t += 64) d = fmaf(xs[t], as[t], d);
#pragma unroll
      for (int off = 32; off > 0; off >>= 1) d += __shfl_xor(d, off);
      if (lane == 0) {
        float cs = d / (nfn * na_arr[b * Ls + k]);
        cs = fminf(fmaxf(cs, -CLIPf), CLIPf);
        ssc[i] = 1.0f - acosf(cs) * (float)(1.0 / M_PI);
      }
    }
    __syncthreads();
    if (threadIdx.x == 0) {
      float mx = -1e30f;
      for (int i = 0; i < nk; ++i) mx = fmaxf(mx, ssc[i]);
      sred[0] = mx;
    }
    __syncthreads();
    const float mx = sred[0];
    if ((int)threadIdx.x < nk) ssc[threadIdx.x] = expf(ssc[threadIdx.x] - mx);
    __syncthreads();
    if (threadIdx.x == 0) {
      float s = 0.f;
      for (int i = 0; i < nk; ++i) s += ssc[i];
      sred[1] = 1.0f / fmaxf(s, EPSf);
    }
    __syncthreads();
    const float inv = sred[1];
    for (int k = threadIdx.x; k < MAXNc; k += 256) {
      float v = 0.f;
      if (k >= k0 && k <= k1) v = 0.5f * ssc[k - k0] * inv;
      orow[k] = v;
    }
  }
}

// ---------------------------------------------------------------------------
// Kernel 4: banded contextual attention via MFMA banded Gram (round-1 exact).
// bf16 knb A-side, kninv precomputed; B-side bf16 ybar (stride KST).
// ---------------------------------------------------------------------------
__global__ __launch_bounds__(512) void con_attn_mfma(const unsigned short* __restrict__ knb,
                                                     const unsigned short* __restrict__ ybar,
                                                     const float* __restrict__ rowss,
                                                     const float* __restrict__ kninv,
                                                     const float* __restrict__ anew,
                                                     const int* __restrict__ tlen,
                                                     float* __restrict__ out) {
  const int b = blockIdx.x / 7;
  const int jt = blockIdx.x % 7;
  const int j0 = jt * 16;
  const int len = tlen[b];
  if (j0 >= len) return;                       // rows already zeroed by sem_attn
  const int kbase = min(max(j0 - WPc, 0), Ls - 48);   // 48-window always in-range

  const int tid = threadIdx.x;
  const int wave = tid >> 6, lane = tid & 63;
  const int quad = lane >> 4, l16 = lane & 15;

  __shared__ float red[8][768];   // 24 KB: per-wave partial 16x48 tiles

  const int jj = min(j0 + l16, Ls - 1);        // A-row clamp (tile may overhang L)
  const size_t blj = (size_t)(b * Ls + jj);

  float outacc[3][4];
#pragma unroll
  for (int t = 0; t < 3; ++t)
#pragma unroll
    for (int r = 0; r < 4; ++r) outacc[t][r] = 0.f;

  const unsigned short* yrow[3];
  int krow_m[3];    // flattened GEMM row index base for (k, n=0)
#pragma unroll
  for (int t = 0; t < 3; ++t) {
    const int k = kbase + t * 16 + l16;
    yrow[t] = ybar + (size_t)(b * Ls + k) * Ns * KST;
    krow_m[t] = (b * Ls + k) * Ns;
  }

  for (int ni = 0; ni < 5; ++ni) {
    const int n = wave + ni * 8;
    const unsigned short* __restrict__ arow =
        knb + ((blj * Ns + n) * (size_t)KST) + quad * 8;

    float w_t[3];
#pragma unroll
    for (int t = 0; t < 3; ++t) {
      const int mm = krow_m[t] + n;
      const float a = anew[mm];
      const float ssqk = rowss[mm];
      const float aff = (sqrtf((a - 0.5f) * (a - 0.5f) + 0.25f * a * a) - 0.06467f) *
                        (1.0f / 0.607468f);
      w_t[t] = aff / fmaxf(aff * sqrtf(ssqk), EPSf);
    }
    const float kinv = kninv[blj * Ns + n];   // fp32-exact 1/||kn(j,n)||

    floatx4 S[3];
#pragma unroll
    for (int t = 0; t < 3; ++t) S[t] = (floatx4){0.f, 0.f, 0.f, 0.f};

#pragma unroll
    for (int c = 0; c < 10; ++c) {
      const short8_t afrag = *reinterpret_cast<const short8_t*>(arow + c * 32);
#pragma unroll
      for (int t = 0; t < 3; ++t) {
        const short8_t bfrag = *reinterpret_cast<const short8_t*>(
            yrow[t] + (size_t)n * KST + c * 32 + quad * 8);
        S[t] = __builtin_amdgcn_mfma_f32_16x16x32_bf16(afrag, bfrag, S[t], 0, 0, 0);
      }
    }

#pragma unroll
    for (int r = 0; r < 4; ++r) {
      const float kv = __shfl(kinv, quad * 4 + r);
#pragma unroll
      for (int t = 0; t < 3; ++t)
        outacc[t][r] = fmaf(kv * w_t[t], fabsf(S[t][r]), outacc[t][r]);
    }
  }

#pragma unroll
  for (int t = 0; t < 3; ++t)
#pragma unroll
    for (int r = 0; r < 4; ++r)
      red[wave][(quad * 4 + r) * 48 + t * 16 + l16] = outacc[t][r];
  __syncthreads();

  for (int idx = tid; idx < 768; idx += 512) {
    float s = 0.f;
#pragma unroll
    for (int w = 0; w < 8; ++w) s += red[w][idx];
    const int j = j0 + idx / 48;
    const int k = kbase + idx % 48;
    if (j < len && k < len && k >= j - WPc && k <= j + WFc)
      out[(size_t)(b * Ls + j) * MAXNc + k] += 5.0f * s;   // 0.5 * 10
  }
}

// ---------------------------------------------------------------------------
extern "C" void kernel_launch(void* const* d_in, const int* in_sizes, int n_in,
                              void* d_out, int out_size, void* d_ws, size_t ws_size,
                              hipStream_t stream) {
  const float* nf   = (const float*)d_in[0];   // (B,L,G)
  const float* kn   = (const float*)d_in[1];   // (B,L,N,D)
  const float* anew = (const float*)d_in[2];   // (B,L,N)
  const float* wsem = (const float*)d_in[3];   // (G,G)
  const float* wcon = (const float*)d_in[4];   // (D,D)
  const int*   tlen = (const int*)d_in[5];     // (B,)
  float* out = (float*)d_out;

  // workspace layout (~190 MB)
  float* att_sem = (float*)d_ws;                            // 3520*512 f32
  float* na_arr  = att_sem + (size_t)BL * Gs;               // 3520 f32
  float* wt      = na_arr + BL;                             // 512*512 f32
  short* wct     = (short*)(wt + (size_t)Gs * Gs);          // 320*320 bf16
  float* rowss   = (float*)(wct + KST * KST);               // Mrows f32
  float* kninv   = rowss + Mrows;                           // Mrows f32
  unsigned short* knb  = (unsigned short*)(kninv + Mrows);  // Mrows*320 bf16
  unsigned short* ybar = knb + (size_t)Mrows * KST;         // Mrows*320 bf16

  hipMemsetAsync(rowss, 0, (size_t)Mrows * sizeof(float), stream);
  transpose_wsem<<<dim3(16, 16), dim3(32, 8), 0, stream>>>(wsem, wt);
  wct_prep<<<dim3(10, 10), dim3(32, 8), 0, stream>>>(wcon, wct);
  // fused1: kn_prep (2048 blocks) || sem_gemm (440 blocks)
  fused_prep_semgemm<<<PREP_BLOCKS + SGEMM_BLOCKS, 512, 0, stream>>>(
      kn, knb, kninv, nf, wt, att_sem, na_arr);
  // fused2: con_gemm (2208 blocks) || sem_attn (3520 blocks)
  fused_congemm_semattn<<<CGEMM_BLOCKS + BL, 256, 0, stream>>>(
      knb, wct, tlen, ybar, rowss, nf, att_sem, na_arr, out);
  con_attn_mfma<<<Bb * 7, 512, 0, stream>>>(knb, ybar, rowss, kninv, anew, tlen, out);
}

// Round 9
// 484.734 us; speedup vs baseline: 1.4420x; 1.0337x over previous
//
#include <hip/hip_runtime.h>
#include <hip/hip_bf16.h>
#include <math.h>

// Problem constants (from reference)
constexpr int Bb   = 32;
constexpr int Ls   = 110;
constexpr int Gs   = 512;
constexpr int Ns   = 40;
constexpr int Ds   = 300;
constexpr int WPc  = 10;
constexpr int WFc  = 10;
constexpr int MAXNc = 110;
constexpr float EPSf  = 1e-8f;
constexpr float CLIPf = 1.0f - 1e-6f;
constexpr int BL = Bb * Ls;        // 3520
constexpr int Mrows = BL * Ns;     // 140800 flattened GEMM rows
constexpr int BPITCH = 328;        // LDS B pitch in shorts
constexpr int KST = 320;           // padded bf16 row stride (shorts)
constexpr int RGRP = Mrows / 256;  // 550 row-groups of 256
constexpr int CGEMM_BLOCKS = 2208; // 8 XCDs * 276 slots

typedef __attribute__((ext_vector_type(8))) short short8_t;
typedef __attribute__((ext_vector_type(4))) float floatx4;

__device__ __forceinline__ unsigned short bf16r(float f) {
  unsigned u = __float_as_uint(f);
  u += 0x7fffu + ((u >> 16) & 1u);          // RNE to bf16
  return (unsigned short)(u >> 16);
}

__device__ __forceinline__ unsigned pkbf(float lo, float hi) {
  unsigned a = __float_as_uint(lo), b = __float_as_uint(hi);
  a += 0x7fffu + ((a >> 16) & 1u);
  b += 0x7fffu + ((b >> 16) & 1u);
  return (a >> 16) | (b & 0xffff0000u);
}

__device__ __forceinline__ short8_t cvt8(const float4 v0, const float4 v1) {
  union { short8_t s; unsigned u[4]; } p;
  p.u[0] = pkbf(v0.x, v0.y);
  p.u[1] = pkbf(v0.z, v0.w);
  p.u[2] = pkbf(v1.x, v1.y);
  p.u[3] = pkbf(v1.z, v1.w);
  return p.s;
}

// ---------------------------------------------------------------------------
// Kernel 0: transpose W_sem (512x512) so the sem GEMM reads it coalesced.
// ---------------------------------------------------------------------------
__global__ __launch_bounds__(256) void transpose_wsem(const float* __restrict__ w,
                                                      float* __restrict__ wt) {
  __shared__ float tile[32][33];
  const int bx = blockIdx.x * 32;
  const int by = blockIdx.y * 32;
  const int tx = threadIdx.x;   // 0..31
  const int ty = threadIdx.y;   // 0..7
#pragma unroll
  for (int r = ty; r < 32; r += 8)
    tile[r][tx] = w[(by + r) * Gs + (bx + tx)];
  __syncthreads();
#pragma unroll
  for (int r = ty; r < 32; r += 8)
    wt[(bx + r) * Gs + (by + tx)] = tile[tx][r];   // wt[t][s] = w[s][t]
}

// ---------------------------------------------------------------------------
// Kernel 0b: WcT[t][s] = bf16(Wc[s][t]), zero-padded to [320][320].
// ---------------------------------------------------------------------------
__global__ __launch_bounds__(256) void wct_prep(const float* __restrict__ wc,
                                                short* __restrict__ wct) {
  __shared__ float tile[32][33];
  const int t0 = blockIdx.x * 32;   // t tile
  const int s0 = blockIdx.y * 32;   // s tile
  const int tx = threadIdx.x, ty = threadIdx.y;
#pragma unroll
  for (int r = ty; r < 32; r += 8) {
    const int s = s0 + r, t = t0 + tx;
    tile[r][tx] = (s < Ds && t < Ds) ? wc[s * Ds + t] : 0.f;
  }
  __syncthreads();
#pragma unroll
  for (int r = ty; r < 32; r += 8) {
    const int t = t0 + r, s = s0 + tx;
    wct[t * KST + s] = (short)bf16r(tile[tx][r]);
  }
}

// ---------------------------------------------------------------------------
// Kernel 0c (r1 exact): kn fp32 -> bf16 [Mrows][320] + fp32-exact inv-norms.
// ---------------------------------------------------------------------------
__global__ __launch_bounds__(256) void kn_prep(const float* __restrict__ kn,
                                               unsigned short* __restrict__ knb,
                                               float* __restrict__ kninv) {
  const int wid = (blockIdx.x * 256 + threadIdx.x) >> 6;
  const int lane = threadIdx.x & 63;
  const int nwaves = gridDim.x * 4;
  for (int row = wid; row < Mrows; row += nwaves) {
    const float* __restrict__ src = kn + (size_t)row * Ds;
    float4 v0 = make_float4(0.f, 0.f, 0.f, 0.f);
    float4 v1 = v0;
    const int d0 = lane * 8;
    if (lane < 37) {                      // d0+7 <= 295 < 300 : full
      v0 = *reinterpret_cast<const float4*>(src + d0);
      v1 = *reinterpret_cast<const float4*>(src + d0 + 4);
    } else if (lane == 37) {              // d 296..299 valid, 300..303 zero
      v0 = *reinterpret_cast<const float4*>(src + d0);
    }
    float ss = v0.x * v0.x + v0.y * v0.y + v0.z * v0.z + v0.w * v0.w +
               v1.x * v1.x + v1.y * v1.y + v1.z * v1.z + v1.w * v1.w;
#pragma unroll
    for (int off = 32; off > 0; off >>= 1) ss += __shfl_xor(ss, off);
    if (lane < 40)
      *reinterpret_cast<short8_t*>(knb + (size_t)row * KST + d0) = cvt8(v0, v1);
    if (lane == 0) kninv[row] = 1.0f / fmaxf(sqrtf(ss), EPSf);
  }
}

// ---------------------------------------------------------------------------
// Kernel 1 (round-9 rewrite): att_sem[bl,s] = sum_t W[s,t] * x[bl,t].
// Was ~90us at 1.85 GFLOP (issue/latency-bound: scalar 4B wt loads, serial
// acc chain). Now: float4 wt loads (1 KB/wave/iter coalesced, unroll 8 ->
// 8 loads in flight), x rows in LDS (broadcast reads), 2 rows x 4 cols per
// thread (~24 VGPR -> full occupancy). Same fp32 numerics.
// ---------------------------------------------------------------------------
__global__ __launch_bounds__(512) void sem_gemm(const float* __restrict__ nf,
                                                const float* __restrict__ wt,
                                                float* __restrict__ att_sem,
                                                float* __restrict__ na_arr) {
  __shared__ float xs[8][Gs];          // 16 KB
  __shared__ float red[4][2][2];       // [grp][wave-half][row]
  const int bl0 = blockIdx.x * 8;
  const int tid = threadIdx.x;

  // stage the 8 x-rows (contiguous 16 KB, fully coalesced)
  {
    const float* __restrict__ x0 = nf + (size_t)bl0 * Gs;
    const int base = tid * 8;
    const float4 a = *reinterpret_cast<const float4*>(x0 + base);
    const float4 b = *reinterpret_cast<const float4*>(x0 + base + 4);
    *reinterpret_cast<float4*>(&xs[0][0] + base) = a;
    *reinterpret_cast<float4*>(&xs[0][0] + base + 4) = b;
  }
  __syncthreads();

  const int sq = tid & 127;            // s-quad: s = sq*4 .. sq*4+3
  const int g  = tid >> 7;             // 0..3 -> rows 2g, 2g+1
  float4 acc0 = make_float4(0.f, 0.f, 0.f, 0.f);
  float4 acc1 = make_float4(0.f, 0.f, 0.f, 0.f);
  const float* __restrict__ wp = wt + sq * 4;
  const float* __restrict__ xa = &xs[2 * g][0];
  const float* __restrict__ xb = &xs[2 * g + 1][0];

#pragma unroll 8
  for (int t = 0; t < Gs; ++t) {
    const float4 wv = *reinterpret_cast<const float4*>(wp + (size_t)t * Gs);
    const float va = xa[t];             // LDS broadcast within each grp
    const float vb = xb[t];
    acc0.x = fmaf(wv.x, va, acc0.x);
    acc0.y = fmaf(wv.y, va, acc0.y);
    acc0.z = fmaf(wv.z, va, acc0.z);
    acc0.w = fmaf(wv.w, va, acc0.w);
    acc1.x = fmaf(wv.x, vb, acc1.x);
    acc1.y = fmaf(wv.y, vb, acc1.y);
    acc1.z = fmaf(wv.z, vb, acc1.z);
    acc1.w = fmaf(wv.w, vb, acc1.w);
  }

  *reinterpret_cast<float4*>(&att_sem[(size_t)(bl0 + 2 * g) * Gs + sq * 4]) = acc0;
  *reinterpret_cast<float4*>(&att_sem[(size_t)(bl0 + 2 * g + 1) * Gs + sq * 4]) = acc1;

  float s0 = acc0.x * acc0.x + acc0.y * acc0.y + acc0.z * acc0.z + acc0.w * acc0.w;
  float s1 = acc1.x * acc1.x + acc1.y * acc1.y + acc1.z * acc1.z + acc1.w * acc1.w;
#pragma unroll
  for (int off = 32; off > 0; off >>= 1) {
    s0 += __shfl_xor(s0, off);
    s1 += __shfl_xor(s1, off);
  }
  const int half = (tid >> 6) & 1;
  if ((tid & 63) == 0) {
    red[g][half][0] = s0;
    red[g][half][1] = s1;
  }
  __syncthreads();
  if (tid < 8) {
    const int gg = tid >> 1, rr = tid & 1;
    const float sum = red[gg][0][rr] + red[gg][1][rr];
    na_arr[bl0 + 2 * gg + rr] = fmaxf(sqrtf(sum), EPSf);
  }
}

// ---------------------------------------------------------------------------
// FUSED 2 (r8 exact, it won ~10us): con_gemm (blocks [0,2208), r1 body:
// knb A-side ring-3, LDS-staged B, 4 row-tiles/wave) CONCURRENT WITH
// sem_attn (blocks [2208,5728)). sem_attn's ~2 KB LDS overlays Bl.
// ---------------------------------------------------------------------------
__global__ __launch_bounds__(256, 3) void fused_congemm_semattn(
    const unsigned short* __restrict__ knb, const short* __restrict__ wct,
    const int* __restrict__ tlen,
    unsigned short* __restrict__ ybar, float* __restrict__ rowss,
    const float* __restrict__ nf, const float* __restrict__ att_sem,
    const float* __restrict__ na_arr, float* __restrict__ out) {
  __shared__ short Bl[80 * BPITCH];   // 52.5 KB; overlaid by sem_attn branch
  __shared__ float sred[4];
  __shared__ float ssc[21];

  if (blockIdx.x < CGEMM_BLOCKS) {
    // ---- con_gemm (r1 body) ----
    const int lin = blockIdx.x;
    const int xcd = lin & 7, slot = lin >> 3;
    const int m = slot & 3;
    const int g = xcd + 8 * (slot >> 2);
    if (g >= RGRP) return;
    const int rowbase = g * 256;
    const int n0 = m * 80;

    const int tid = threadIdx.x;
    for (int s = tid; s < 80 * 40; s += 256) {
      const int nl = s / 40, sl = s % 40;
      *reinterpret_cast<short8_t*>(&Bl[nl * BPITCH + sl * 8]) =
          *reinterpret_cast<const short8_t*>(wct + (n0 + nl) * KST + sl * 8);
    }
    __syncthreads();   // the only barrier in this branch

    const int wave = tid >> 6, lane = tid & 63;
    const int quad = lane >> 4, l16 = lane & 15;
    const int wrow = rowbase + wave * 64;   // 64 rows per wave

    {
      bool any = false;
      for (int bl = wrow / Ns; bl <= (wrow + 63) / Ns; ++bl)
        any |= (bl % Ls) < tlen[bl / Ls];
      if (!any) return;   // barrier already passed; safe
    }

    const unsigned short* arow[4];
#pragma unroll
    for (int tt = 0; tt < 4; ++tt)
      arow[tt] = knb + (size_t)(wrow + tt * 16 + l16) * KST + quad * 8;

    floatx4 acc[4][5];
#pragma unroll
    for (int tt = 0; tt < 4; ++tt)
#pragma unroll
      for (int i = 0; i < 5; ++i) acc[tt][i] = (floatx4){0.f, 0.f, 0.f, 0.f};

    // ring-3 A prefetch (uniform chunks thanks to knb zero-padding)
    short8_t A[3][4];
#pragma unroll
    for (int tt = 0; tt < 4; ++tt) {
      A[0][tt] = *reinterpret_cast<const short8_t*>(arow[tt]);
      A[1][tt] = *reinterpret_cast<const short8_t*>(arow[tt] + 32);
    }

#pragma unroll
    for (int c = 0; c < 10; ++c) {
      if (c < 8) {
#pragma unroll
        for (int tt = 0; tt < 4; ++tt)
          A[(c + 2) % 3][tt] =
              *reinterpret_cast<const short8_t*>(arow[tt] + (c + 2) * 32);
      }
#pragma unroll
      for (int i = 0; i < 5; ++i) {
        const short8_t bfrag = *reinterpret_cast<const short8_t*>(
            &Bl[(i * 16 + l16) * BPITCH + c * 32 + quad * 8]);
#pragma unroll
        for (int tt = 0; tt < 4; ++tt)
          acc[tt][i] = __builtin_amdgcn_mfma_f32_16x16x32_bf16(
              A[c % 3][tt], bfrag, acc[tt][i], 0, 0, 0);
      }
    }

    // epilogue: per-tile liveness guard; row-ssq atomics + bf16 store
#pragma unroll
    for (int tt = 0; tt < 4; ++tt) {
      const int row0 = wrow + tt * 16;
      const int blA = row0 / Ns, blB = (row0 + 15) / Ns;
      const bool alive =
          ((blA % Ls) < tlen[blA / Ls]) | ((blB % Ls) < tlen[blB / Ls]);
      if (!alive) continue;

#pragma unroll
      for (int r = 0; r < 4; ++r) {
        float p = 0.f;
#pragma unroll
        for (int i = 0; i < 5; ++i) p = fmaf(acc[tt][i][r], acc[tt][i][r], p);
        p += __shfl_xor(p, 1);
        p += __shfl_xor(p, 2);
        p += __shfl_xor(p, 4);
        p += __shfl_xor(p, 8);
        if (l16 == 0) atomicAdd(&rowss[row0 + quad * 4 + r], p);
      }
#pragma unroll
      for (int i = 0; i < 5; ++i) {
        const int col = n0 + i * 16 + l16;   // < 320 always
#pragma unroll
        for (int r = 0; r < 4; ++r)
          ybar[(size_t)(row0 + quad * 4 + r) * KST + col] = bf16r(acc[tt][i][r]);
      }
    }
  } else {
    // ---- sem_attn (r1 body; xs overlaid on Bl) ----
    float* xs = reinterpret_cast<float*>(Bl);   // 512 floats = 2 KB < 52.5 KB
    const int blk = blockIdx.x - CGEMM_BLOCKS;
    const int b = blk / Ls, j = blk % Ls;
    const int len = tlen[b];
    float* __restrict__ orow = out + (size_t)(b * Ls + j) * MAXNc;
    if (j >= len) {
      for (int k = threadIdx.x; k < MAXNc; k += 256) orow[k] = 0.f;
      return;
    }
    const int k0 = max(j - WPc, 0);
    const int k1 = min(j + WFc, len - 1);
    const int nk = k1 - k0 + 1;   // <= 21

    const float* __restrict__ x = nf + (size_t)(b * Ls + j) * Gs;
    float ss = 0.f;
    for (int t = threadIdx.x; t < Gs; t += 256) {
      const float v = x[t];
      xs[t] = v;
      ss += v * v;
    }
    const int wave = threadIdx.x >> 6, lane = threadIdx.x & 63;
#pragma unroll
    for (int off = 32; off > 0; off >>= 1) ss += __shfl_xor(ss, off);
    if (lane == 0) sred[wave] = ss;
    __syncthreads();
    const float nfn = fmaxf(sqrtf(sred[0] + sred[1] + sred[2] + sred[3]), EPSf);

    for (int i = wave; i < nk; i += 4) {
      const int k = k0 + i;
      const float* __restrict__ as = att_sem + (size_t)(b * Ls + k) * Gs;
      float d = 0.f;
#pragma unroll
      for (int t = lane; t < Gs; t += 64) d = fmaf(xs[t], as[t], d);
#pragma unroll
      for (int off = 32; off > 0; off >>= 1) d += __shfl_xor(d, off);
      if (lane == 0) {
        float cs = d / (nfn * na_arr[b * Ls + k]);
        cs = fminf(fmaxf(cs, -CLIPf), CLIPf);
        ssc[i] = 1.0f - acosf(cs) * (float)(1.0 / M_PI);
      }
    }
    __syncthreads();
    if (threadIdx.x == 0) {
      float mx = -1e30f;
      for (int i = 0; i < nk; ++i) mx = fmaxf(mx, ssc[i]);
      sred[0] = mx;
    }
    __syncthreads();
    const float mx = sred[0];
    if ((int)threadIdx.x < nk) ssc[threadIdx.x] = expf(ssc[threadIdx.x] - mx);
    __syncthreads();
    if (threadIdx.x == 0) {
      float s = 0.f;
      for (int i = 0; i < nk; ++i) s += ssc[i];
      sred[1] = 1.0f / fmaxf(s, EPSf);
    }
    __syncthreads();
    const float inv = sred[1];
    for (int k = threadIdx.x; k < MAXNc; k += 256) {
      float v = 0.f;
      if (k >= k0 && k <= k1) v = 0.5f * ssc[k - k0] * inv;
      orow[k] = v;
    }
  }
}

// ---------------------------------------------------------------------------
// Kernel 4: banded contextual attention via MFMA banded Gram (r1 exact).
// bf16 knb A-side, kninv precomputed; B-side bf16 ybar (stride KST).
// ---------------------------------------------------------------------------
__global__ __launch_bounds__(512) void con_attn_mfma(const unsigned short* __restrict__ knb,
                                                     const unsigned short* __restrict__ ybar,
                                                     const float* __restrict__ rowss,
                                                     const float* __restrict__ kninv,
                                                     const float* __restrict__ anew,
                                                     const int* __restrict__ tlen,
                                                     float* __restrict__ out) {
  const int b = blockIdx.x / 7;
  const int jt = blockIdx.x % 7;
  const int j0 = jt * 16;
  const int len = tlen[b];
  if (j0 >= len) return;                       // rows already zeroed by sem_attn
  const int kbase = min(max(j0 - WPc, 0), Ls - 48);   // 48-window always in-range

  const int tid = threadIdx.x;
  const int wave = tid >> 6, lane = tid & 63;
  const int quad = lane >> 4, l16 = lane & 15;

  __shared__ float red[8][768];   // 24 KB: per-wave partial 16x48 tiles

  const int jj = min(j0 + l16, Ls - 1);        // A-row clamp (tile may overhang L)
  const size_t blj = (size_t)(b * Ls + jj);

  float outacc[3][4];
#pragma unroll
  for (int t = 0; t < 3; ++t)
#pragma unroll
    for (int r = 0; r < 4; ++r) outacc[t][r] = 0.f;

  const unsigned short* yrow[3];
  int krow_m[3];    // flattened GEMM row index base for (k, n=0)
#pragma unroll
  for (int t = 0; t < 3; ++t) {
    const int k = kbase + t * 16 + l16;
    yrow[t] = ybar + (size_t)(b * Ls + k) * Ns * KST;
    krow_m[t] = (b * Ls + k) * Ns;
  }

  for (int ni = 0; ni < 5; ++ni) {
    const int n = wave + ni * 8;
    const unsigned short* __restrict__ arow =
        knb + ((blj * Ns + n) * (size_t)KST) + quad * 8;

    float w_t[3];
#pragma unroll
    for (int t = 0; t < 3; ++t) {
      const int mm = krow_m[t] + n;
      const float a = anew[mm];
      const float ssqk = rowss[mm];
      const float aff = (sqrtf((a - 0.5f) * (a - 0.5f) + 0.25f * a * a) - 0.06467f) *
                        (1.0f / 0.607468f);
      w_t[t] = aff / fmaxf(aff * sqrtf(ssqk), EPSf);
    }
    const float kinv = kninv[blj * Ns + n];   // fp32-exact 1/||kn(j,n)||

    floatx4 S[3];
#pragma unroll
    for (int t = 0; t < 3; ++t) S[t] = (floatx4){0.f, 0.f, 0.f, 0.f};

#pragma unroll
    for (int c = 0; c < 10; ++c) {
      const short8_t afrag = *reinterpret_cast<const short8_t*>(arow + c * 32);
#pragma unroll
      for (int t = 0; t < 3; ++t) {
        const short8_t bfrag = *reinterpret_cast<const short8_t*>(
            yrow[t] + (size_t)n * KST + c * 32 + quad * 8);
        S[t] = __builtin_amdgcn_mfma_f32_16x16x32_bf16(afrag, bfrag, S[t], 0, 0, 0);
      }
    }

#pragma unroll
    for (int r = 0; r < 4; ++r) {
      const float kv = __shfl(kinv, quad * 4 + r);
#pragma unroll
      for (int t = 0; t < 3; ++t)
        outacc[t][r] = fmaf(kv * w_t[t], fabsf(S[t][r]), outacc[t][r]);
    }
  }

#pragma unroll
  for (int t = 0; t < 3; ++t)
#pragma unroll
    for (int r = 0; r < 4; ++r)
      red[wave][(quad * 4 + r) * 48 + t * 16 + l16] = outacc[t][r];
  __syncthreads();

  for (int idx = tid; idx < 768; idx += 512) {
    float s = 0.f;
#pragma unroll
    for (int w = 0; w < 8; ++w) s += red[w][idx];
    const int j = j0 + idx / 48;
    const int k = kbase + idx % 48;
    if (j < len && k < len && k >= j - WPc && k <= j + WFc)
      out[(size_t)(b * Ls + j) * MAXNc + k] += 5.0f * s;   // 0.5 * 10
  }
}

// ---------------------------------------------------------------------------
extern "C" void kernel_launch(void* const* d_in, const int* in_sizes, int n_in,
                              void* d_out, int out_size, void* d_ws, size_t ws_size,
                              hipStream_t stream) {
  const float* nf   = (const float*)d_in[0];   // (B,L,G)
  const float* kn   = (const float*)d_in[1];   // (B,L,N,D)
  const float* anew = (const float*)d_in[2];   // (B,L,N)
  const float* wsem = (const float*)d_in[3];   // (G,G)
  const float* wcon = (const float*)d_in[4];   // (D,D)
  const int*   tlen = (const int*)d_in[5];     // (B,)
  float* out = (float*)d_out;

  // workspace layout (~190 MB)
  float* att_sem = (float*)d_ws;                            // 3520*512 f32
  float* na_arr  = att_sem + (size_t)BL * Gs;               // 3520 f32
  float* wt      = na_arr + BL;                             // 512*512 f32
  short* wct     = (short*)(wt + (size_t)Gs * Gs);          // 320*320 bf16
  float* rowss   = (float*)(wct + KST * KST);               // Mrows f32
  float* kninv   = rowss + Mrows;                           // Mrows f32
  unsigned short* knb  = (unsigned short*)(kninv + Mrows);  // Mrows*320 bf16
  unsigned short* ybar = knb + (size_t)Mrows * KST;         // Mrows*320 bf16

  hipMemsetAsync(rowss, 0, (size_t)Mrows * sizeof(float), stream);
  transpose_wsem<<<dim3(16, 16), dim3(32, 8), 0, stream>>>(wsem, wt);
  wct_prep<<<dim3(10, 10), dim3(32, 8), 0, stream>>>(wcon, wct);
  kn_prep<<<2048, 256, 0, stream>>>(kn, knb, kninv);
  sem_gemm<<<BL / 8, 512, 0, stream>>>(nf, wt, att_sem, na_arr);
  // fused2: con_gemm (2208 blocks) || sem_attn (3520 blocks)
  fused_congemm_semattn<<<CGEMM_BLOCKS + BL, 256, 0, stream>>>(
      knb, wct, tlen, ybar, rowss, nf, att_sem, na_arr, out);
  con_attn_mfma<<<Bb * 7, 512, 0, stream>>>(knb, ybar, rowss, kninv, anew, tlen, out);
}